// Round 1
// baseline (453.156 us; speedup 1.0000x reference)
//
#include <hip/hip_runtime.h>

// LGA (GANet Local Guided Aggregation), radius=2, K=5.
// in1: [N=4, C=32, H=384, W=768] f32
// in2: [N=4, 25,   H=384, W=768] f32 (per-pixel 5x5 taps, shared across C)
// out: [N, C, H, W] f32
//
// Strategy: memory-bound (~420 MB ideal). Thread owns 4 consecutive pixels,
// holds their 25 tap weights in VGPRs (25x float4 = 100 VGPRs) across the
// channel loop so in2 is read exactly once. Per channel, input1 tile+halo is
// staged in LDS (stored shifted -2 cols so each thread's 8-float window is
// 16B aligned -> 2x ds_read_b128 per row, bank-bandwidth-optimal at 16B lane
// stride).

#define N_DIM 4
#define C_DIM 32
#define H_DIM 384
#define W_DIM 768
#define TH 4          // output rows per block
#define TW 256        // output cols per block (64 lanes x 4 pixels)
#define LROWS (TH + 4)
#define LW 260        // LDS row stride in floats: holds global cols [w0-2, w0+258)

__global__ __launch_bounds__(256, 3)
void lga_kernel(const float* __restrict__ in1,
                const float* __restrict__ in2,
                float* __restrict__ out) {
    __shared__ float lds[LROWS * LW];

    const int tid = threadIdx.x;
    const int tx  = tid & 63;   // lane within wave
    const int ty  = tid >> 6;   // wave index = output row within tile
    const int w0  = blockIdx.x * TW;
    const int h0  = blockIdx.y * TH;
    const int n   = blockIdx.z;

    const int h   = h0 + ty;          // this thread's output row
    const int wb  = w0 + 4 * tx;      // first of 4 output cols

    // ---- load this thread's 25 per-pixel weights (float4 = 4 pixels) ----
    float4 wt[25];
    const float* w_src = in2 + ((size_t)n * 25) * (H_DIM * W_DIM)
                             + (size_t)h * W_DIM + wb;
#pragma unroll
    for (int t = 0; t < 25; ++t) {
        wt[t] = *(const float4*)(w_src + (size_t)t * (H_DIM * W_DIM));
    }

    const float* in1_n = in1 + (size_t)n * C_DIM * H_DIM * W_DIM;
    float*       out_n = out + (size_t)n * C_DIM * H_DIM * W_DIM;

    for (int c = 0; c < C_DIM; ++c) {
        const float* src = in1_n + (size_t)c * (H_DIM * W_DIM);

        // ---- stage rows [h0-2, h0+TH+2) x cols [w0-2, w0+TW+2) into LDS ----
        // LDS col L maps to global col (w0 - 2 + L); chunk = 4 floats.
        for (int idx = tid; idx < LROWS * 65; idx += 256) {
            const int row = idx / 65;
            const int c4  = idx - row * 65;
            const int gh  = h0 - 2 + row;
            const int g   = w0 - 2 + 4 * c4;   // global col of chunk start (== 2 mod 4)
            float4 v;
            if ((unsigned)gh < H_DIM && g >= 0 && g + 3 < W_DIM) {
                const float* p = src + gh * W_DIM + g;   // 8B aligned
                const float2 a = *(const float2*)p;
                const float2 b = *(const float2*)(p + 2);
                v = make_float4(a.x, a.y, b.x, b.y);
            } else {
                const bool rok = (unsigned)gh < H_DIM;
                const float* prow = src + gh * W_DIM;
                v.x = (rok && (unsigned)(g + 0) < W_DIM) ? prow[g + 0] : 0.f;
                v.y = (rok && (unsigned)(g + 1) < W_DIM) ? prow[g + 1] : 0.f;
                v.z = (rok && (unsigned)(g + 2) < W_DIM) ? prow[g + 2] : 0.f;
                v.w = (rok && (unsigned)(g + 3) < W_DIM) ? prow[g + 3] : 0.f;
            }
            *(float4*)&lds[row * LW + 4 * c4] = v;       // 16B aligned (LW*4 = 65*16)
        }
        __syncthreads();

        // ---- compute 4 pixels ----
        float acc0 = 0.f, acc1 = 0.f, acc2 = 0.f, acc3 = 0.f;
#pragma unroll
        for (int i = 0; i < 5; ++i) {
            const float* lrow = &lds[(ty + i) * LW + 4 * tx];  // global col wb-2
            const float4 A = *(const float4*)lrow;             // win[0..3]
            const float4 B = *(const float4*)(lrow + 4);       // win[4..7]
            const float win[8] = {A.x, A.y, A.z, A.w, B.x, B.y, B.z, B.w};
#pragma unroll
            for (int j = 0; j < 5; ++j) {
                const float4 wv = wt[5 * i + j];
                acc0 += wv.x * win[j + 0];
                acc1 += wv.y * win[j + 1];
                acc2 += wv.z * win[j + 2];
                acc3 += wv.w * win[j + 3];
            }
        }

        *(float4*)(out_n + (size_t)c * (H_DIM * W_DIM) + (size_t)h * W_DIM + wb)
            = make_float4(acc0, acc1, acc2, acc3);
        __syncthreads();   // protect LDS before next channel's staging
    }
}

extern "C" void kernel_launch(void* const* d_in, const int* in_sizes, int n_in,
                              void* d_out, int out_size, void* d_ws, size_t ws_size,
                              hipStream_t stream) {
    const float* in1 = (const float*)d_in[0];
    const float* in2 = (const float*)d_in[1];
    float* out = (float*)d_out;
    dim3 grid(W_DIM / TW, H_DIM / TH, N_DIM);   // (3, 96, 4)
    lga_kernel<<<grid, 256, 0, stream>>>(in1, in2, out);
}